// Round 13
// baseline (341.413 us; speedup 1.0000x reference)
//
#include <hip/hip_runtime.h>
#include <math.h>

#define BATCH 16
#define CH    128
#define HGT   56
#define WID   56
#define NPIX  (BATCH*HGT*WID)   // 50176
#define NQKV  384
#define NWIN  7
#define P2    49
#define TOPK  4
#define ATT_SCALE 0.088388347648318447f   // 128^-0.5

typedef __attribute__((ext_vector_type(8))) short short8;
typedef __attribute__((ext_vector_type(4))) short short4v;
typedef __attribute__((ext_vector_type(4))) float float4v;

static __device__ __forceinline__ unsigned short f2bf(float f) {
  unsigned u = __float_as_uint(f);
  u += 0x7fffu + ((u >> 16) & 1u);   // round-to-nearest-even
  return (unsigned short)(u >> 16);
}
static __device__ __forceinline__ float bf2f(unsigned short u) {
  return __uint_as_float((unsigned)u << 16);
}

// ---------------------------------------------------------------------------
// K0: weight prep — convert to bf16 and transpose to [N][K] layout.
// ---------------------------------------------------------------------------
__global__ __launch_bounds__(128) void k_prep(
    const float* __restrict__ qkv_w, const float* __restrict__ wo_w,
    const float* __restrict__ mlp_w1, const float* __restrict__ mlp_w2,
    unsigned short* __restrict__ Wq, unsigned short* __restrict__ Wo,
    unsigned short* __restrict__ W1, unsigned short* __restrict__ W2) {
  int bx = blockIdx.x, t = threadIdx.x;
  if (bx < 384) {
    int n = bx;
    Wq[n*128 + t] = f2bf(qkv_w[(size_t)t*384 + n]);
  } else if (bx < 512) {
    int n = bx - 384;
    Wo[n*128 + t] = f2bf(wo_w[(size_t)t*128 + n]);
  } else if (bx < 896) {
    int n = bx - 512;
    W1[n*128 + t] = f2bf(mlp_w1[(size_t)t*384 + n]);
  } else {
    int n = bx - 896;
    for (int k = t; k < 384; k += 128)
      W2[n*384 + k] = f2bf(mlp_w2[(size_t)k*128 + n]);
  }
}

// ---------------------------------------------------------------------------
// K1: x(NCHW) -> xh(NHWC) = x + dwconv3x3(x).  LDS-staged transpose.
// ---------------------------------------------------------------------------
__global__ __launch_bounds__(256) void k_posconv(const float* __restrict__ x,
    const float* __restrict__ pw, const float* __restrict__ pb,
    float* __restrict__ xh) {
  __shared__ float sh[10*58*32];
  int b = blockIdx.y;
  int rg = blockIdx.x >> 2, cg = blockIdx.x & 3;
  int row0 = rg*8, c0 = cg*32;
  int t = threadIdx.x;
  for (int i = t; i < 10*58*32/4; i += 256)
    ((int4*)sh)[i] = make_int4(0,0,0,0);
  __syncthreads();
  for (int i = t; i < 4480; i += 256) {
    int c = i & 31, chunk = (i >> 5) % 14, rr = i / 448;
    int grow = row0 + rr - 1;
    if ((unsigned)grow < HGT) {
      float4 v = *(const float4*)(x + ((size_t)(b*CH + c0 + c))*(HGT*WID)
                                  + grow*WID + chunk*4);
      float* d = &sh[(rr*58 + 1 + chunk*4)*32 + c];
      d[0] = v.x; d[32] = v.y; d[64] = v.z; d[96] = v.w;
    }
  }
  __syncthreads();
  int c = t & 31, pg = t >> 5;
  float w[9];
#pragma unroll
  for (int i = 0; i < 9; i++) w[i] = pw[(c0 + c)*9 + i];
  float bias = pb[c0 + c];
  const float* rowp[3];
#pragma unroll
  for (int dy = 0; dy < 3; dy++) rowp[dy] = &sh[((pg + dy)*58)*32 + c];
  float win[3][3];
#pragma unroll
  for (int j = 0; j < 2; j++)
#pragma unroll
    for (int dy = 0; dy < 3; dy++) win[j][dy] = rowp[dy][j*32];
  float* ob = &xh[(((size_t)b*HGT + row0 + pg)*WID)*CH + c0 + c];
#pragma unroll
  for (int col = 0; col < 56; col++) {
    int slot = (col + 2) % 3;
#pragma unroll
    for (int dy = 0; dy < 3; dy++) win[slot][dy] = rowp[dy][(col + 2)*32];
    float s = bias + win[(col + 1) % 3][1];
#pragma unroll
    for (int dx = 0; dx < 3; dx++) {
      int sl = (col + dx) % 3;
#pragma unroll
      for (int dy = 0; dy < 3; dy++) s += win[sl][dy] * w[dy*3 + dx];
    }
    ob[col*CH] = s;
  }
}

// ---------------------------------------------------------------------------
// K_route: per window, LN(xh) -> window-mean ym -> qwin/kwin = ym@W + b.
// ---------------------------------------------------------------------------
__global__ __launch_bounds__(256) void k_route(const float* __restrict__ xh,
    const float* __restrict__ g, const float* __restrict__ be,
    const float* __restrict__ qkv_w, const float* __restrict__ qkv_b,
    float* __restrict__ qwin, float* __restrict__ kwin) {
  __shared__ float yt[128*68];
  __shared__ float ym[128];
  int bp = blockIdx.x; int b = bp / P2, p = bp % P2;
  int wy = p / NWIN, wx = p % NWIN;
  int t = threadIdx.x;
  int pl = t >> 2, qu = t & 3;
  {
    int hg = wy*8 + (pl >> 3), wg = wx*8 + (pl & 7);
    const float4* src = (const float4*)(xh + (((size_t)b*HGT + hg)*WID + wg)*CH + qu*32);
    float v[32]; float s = 0.f, ss = 0.f;
#pragma unroll
    for (int i = 0; i < 8; i++) {
      float4 f = src[i];
      v[4*i] = f.x; v[4*i+1] = f.y; v[4*i+2] = f.z; v[4*i+3] = f.w;
      s += f.x + f.y + f.z + f.w;
      ss += f.x*f.x + f.y*f.y + f.z*f.z + f.w*f.w;
    }
    s += __shfl_xor(s, 1); ss += __shfl_xor(ss, 1);
    s += __shfl_xor(s, 2); ss += __shfl_xor(ss, 2);
    float m  = s * (1.f/128.f);
    float var = ss * (1.f/128.f) - m*m;
    float rs = rsqrtf(var + 1e-6f);
#pragma unroll
    for (int i = 0; i < 32; i++) {
      int ch = qu*32 + i;
      yt[ch*68 + pl] = (v[i] - m) * rs * g[ch] + be[ch];
    }
  }
  __syncthreads();
  if (t < 128) {
    const float4* col = (const float4*)&yt[t*68];
    float4 a = make_float4(0.f,0.f,0.f,0.f);
#pragma unroll
    for (int i = 0; i < 16; i++) {
      float4 f = col[i];
      a.x += f.x; a.y += f.y; a.z += f.z; a.w += f.w;
    }
    ym[t] = (a.x + a.y + a.z + a.w) * (1.f/64.f);
  }
  __syncthreads();
  {
    int n = t;
    float s = qkv_b[n];
#pragma unroll 4
    for (int c = 0; c < 128; c++) s += ym[c] * qkv_w[(size_t)c*NQKV + n];
    if (n < 128) qwin[(size_t)bp*128 + n] = s;
    else         kwin[(size_t)bp*128 + n - 128] = s;
  }
}

// ---------------------------------------------------------------------------
// K4: routing logits + top-4.
// ---------------------------------------------------------------------------
__global__ __launch_bounds__(256) void k_topk(const float* __restrict__ qwin,
    const float* __restrict__ kwin, int* __restrict__ idx) {
  __shared__ float logits[64];
  int bp = blockIdx.x; int b = bp / P2;
  int t = threadIdx.x;
  int key = t >> 2, qu = t & 3;
  float s = 0.f;
  if (key < P2) {
    const float4* qp = (const float4*)(qwin + (size_t)bp*128 + qu*32);
    const float4* kp = (const float4*)(kwin + ((size_t)b*P2 + key)*128 + qu*32);
#pragma unroll
    for (int i = 0; i < 8; i++) {
      float4 qv = qp[i], kv = kp[i];
      s += qv.x*kv.x + qv.y*kv.y + qv.z*kv.z + qv.w*kv.w;
    }
  }
  s += __shfl_xor(s, 1);
  s += __shfl_xor(s, 2);
  if (qu == 0 && key < P2) logits[key] = s;
  __syncthreads();
  if (t == 0) {
    unsigned long long used = 0ULL;
    for (int tt = 0; tt < TOPK; tt++) {
      float best = -1e30f; int bi = 0;
      for (int q = 0; q < P2; q++) {
        bool ok = !((used >> q) & 1ULL);
        float lv = logits[q];
        if (ok && lv > best) { best = lv; bi = q; }
      }
      used |= 1ULL << bi;
      idx[(size_t)bp*TOPK + tt] = bi;
    }
  }
}

// ---------------------------------------------------------------------------
// K_qkv: LN + MFMA GEMM (aL + bL in LDS, (256,2)).
// bf16 epilogues -> qW (windowed, *scale), kW, vT (planar via aL restage).
// ---------------------------------------------------------------------------
__global__ __launch_bounds__(256, 2) void k_qkv_gemm(
    const float* __restrict__ in, const float* __restrict__ g,
    const float* __restrict__ be, const unsigned short* __restrict__ Wt,
    const float* __restrict__ bias,
    unsigned short* __restrict__ qW, unsigned short* __restrict__ kW,
    unsigned short* __restrict__ vT) {
  __shared__ __align__(16) unsigned short aL[128*136];
  __shared__ __align__(16) unsigned short bL[128*136];
  int base = blockIdx.x * 128;
  int t = threadIdx.x;
  { // ---- LN + A-stage ----
    int r = t >> 1, half = t & 1;
    const float4* src = (const float4*)(in + (size_t)(base + r)*CH + half*64);
    float v[64];
    float s = 0.f, ss = 0.f;
#pragma unroll
    for (int i = 0; i < 16; i++) {
      float4 f = src[i];
      v[4*i] = f.x; v[4*i+1] = f.y; v[4*i+2] = f.z; v[4*i+3] = f.w;
      s += f.x + f.y + f.z + f.w;
      ss += f.x*f.x + f.y*f.y + f.z*f.z + f.w*f.w;
    }
    s += __shfl_xor(s, 1); ss += __shfl_xor(ss, 1);
    float m  = s * (1.f/128.f);
    float var = ss * (1.f/128.f) - m*m;
    float rs = rsqrtf(var + 1e-6f);
    union { unsigned short us[8]; int4 v4; } pk;
#pragma unroll
    for (int c8 = 0; c8 < 8; c8++) {
#pragma unroll
      for (int j = 0; j < 8; j++) {
        int ch = half*64 + c8*8 + j;
        pk.us[j] = f2bf((v[c8*8 + j] - m) * rs * g[ch] + be[ch]);
      }
      *(int4*)&aL[r*136 + half*64 + c8*8] = pk.v4;
    }
  }
  int wid = t >> 6, lane = t & 63;
  int ln = lane & 15, q = lane >> 4;
  int wr = (wid >> 1)*64, wc = (wid & 1)*64;
  for (int chunk = 0; chunk < 3; chunk++) {
    if (chunk) __syncthreads();
    for (int i = t; i < 2048; i += 256) {
      int row = i >> 4, seg = i & 15;
      *(int4*)&bL[row*136 + seg*8] =
          *(const int4*)(Wt + (size_t)(chunk*128 + row)*128 + seg*8);
    }
    __syncthreads();
    float4v acc[4][4];
#pragma unroll
    for (int a = 0; a < 4; a++)
#pragma unroll
      for (int b2 = 0; b2 < 4; b2++)
        acc[a][b2] = (float4v){0.f, 0.f, 0.f, 0.f};
#pragma unroll
    for (int kk = 0; kk < 4; kk++) {
      int ko = kk*32 + q*8;
      short8 af[4], bf[4];
#pragma unroll
      for (int mf = 0; mf < 4; mf++)
        af[mf] = *(const short8*)&aL[(wr + mf*16 + ln)*136 + ko];
#pragma unroll
      for (int nf = 0; nf < 4; nf++)
        bf[nf] = *(const short8*)&bL[(wc + nf*16 + ln)*136 + ko];
#pragma unroll
      for (int mf = 0; mf < 4; mf++)
#pragma unroll
        for (int nf = 0; nf < 4; nf++)
          acc[mf][nf] = __builtin_amdgcn_mfma_f32_16x16x32_bf16(
              af[mf], bf[nf], acc[mf][nf], 0, 0, 0);
    }
    if (chunk < 2) {
      unsigned short* dst = chunk ? kW : qW;
      float sc = chunk ? 1.f : ATT_SCALE;
#pragma unroll
      for (int mf = 0; mf < 4; mf++) {
#pragma unroll
        for (int j = 0; j < 4; j++) {
          int pg = base + wr + mf*16 + q*4 + j;
          int b  = pg / 3136, sp = pg - b*3136;
          int hh = sp / 56, ww = sp - hh*56;
          int p  = (hh >> 3)*NWIN + (ww >> 3);
          int ploc = (hh & 7)*8 + (ww & 7);
          size_t rb = ((size_t)(b*P2 + p)*64 + ploc)*128;
#pragma unroll
          for (int nf = 0; nf < 4; nf++) {
            int col = wc + nf*16 + ln;
            dst[rb + col] = f2bf((acc[mf][nf][j] + bias[chunk*128 + col])*sc);
          }
        }
      }
    } else {
      __syncthreads();   // all aL reads done -> reuse as v staging
#pragma unroll
      for (int mf = 0; mf < 4; mf++)
#pragma unroll
        for (int nf = 0; nf < 4; nf++) {
          int row = wr + mf*16 + q*4;
          int col = wc + nf*16 + ln;
          float b4 = bias[256 + col];
          short4v pk;
#pragma unroll
          for (int j = 0; j < 4; j++) pk[j] = (short)f2bf(acc[mf][nf][j] + b4);
          *(short4v*)&aL[col*136 + row] = pk;
        }
      __syncthreads();
      int c = t >> 1, half = t & 1;
#pragma unroll
      for (int g8 = 0; g8 < 8; g8++) {
        int pg0 = base + half*64 + g8*8;
        int b = pg0 / 3136, sp = pg0 - b*3136;
        *(int4*)(vT + ((size_t)(b*CH + c))*3136 + sp) =
            *(int4*)&aL[c*136 + half*64 + g8*8];
      }
    }
  }
}

// ---------------------------------------------------------------------------
// K5: MFMA attention, no-max softmax, deferred row-sum, XCD-local per image.
// Output o bf16.
// ---------------------------------------------------------------------------
#define PLS 72
__global__ __launch_bounds__(256) void k_attn_mfma(
    const unsigned short* __restrict__ qW, const unsigned short* __restrict__ kW,
    const unsigned short* __restrict__ vT, const int* __restrict__ idx,
    unsigned short* __restrict__ o) {
  __shared__ unsigned short pL[4][64*PLS];
  int bx = blockIdx.x;
  int b = bx & 15, p = bx >> 4;
  int bp = b*P2 + p;
  int wy = p / NWIN, wx = p % NWIN;
  int h = threadIdx.x >> 6, lane = threadIdx.x & 63;
  int ln = lane & 15, q = lane >> 4;

  short8 aq[4];
#pragma unroll
  for (int mf = 0; mf < 4; mf++)
    aq[mf] = *(const short8*)&qW[((size_t)bp*64 + mf*16 + ln)*128 + h*32 + q*8];

  int4 widx = *(const int4*)&idx[(size_t)bp*TOPK];
  int wins[4] = {widx.x, widx.y, widx.z, widx.w};

  float l_run[4][4];
  float4v facc[4][2];
#pragma unroll
  for (int mf = 0; mf < 4; mf++) {
#pragma unroll
    for (int j = 0; j < 4; j++) l_run[mf][j] = 0.f;
    facc[mf][0] = (float4v){0.f,0.f,0.f,0.f};
    facc[mf][1] = (float4v){0.f,0.f,0.f,0.f};
  }

  unsigned short* myP = &pL[h][0];
  int swr = ((ln >> 2) & 3) * 16;

  for (int r = 0; r < TOPK; r++) {
    int win = wins[r];
    int sy = win / NWIN, sx = win % NWIN;
    short8 bk[4];
#pragma unroll
    for (int nf = 0; nf < 4; nf++)
      bk[nf] = *(const short8*)&kW[(((size_t)b*P2 + win)*64 + nf*16 + ln)*128 + h*32 + q*8];
    float4v sacc[4][4];
#pragma unroll
    for (int mf = 0; mf < 4; mf++)
#pragma unroll
      for (int nf = 0; nf < 4; nf++)
        sacc[mf][nf] = (float4v){0.f,0.f,0.f,0.f};
#pragma unroll
    for (int mf = 0; mf < 4; mf++)
#pragma unroll
      for (int nf = 0; nf < 4; nf++)
        sacc[mf][nf] = __builtin_amdgcn_mfma_f32_16x16x32_bf16(
            aq[mf], bk[nf], sacc[mf][nf], 0, 0, 0);
#pragma unroll
    for (int mf = 0; mf < 4; mf++) {
#pragma unroll
      for (int j = 0; j < 4; j++) {
        float e0 = __expf(sacc[mf][0][j]);
        float e1 = __expf(sacc[mf][1][j]);
        float e2 = __expf(sacc[mf][2][j]);
        float e3 = __expf(sacc[mf][3][j]);
        l_run[mf][j] += (e0 + e1) + (e2 + e3);
        int rowoff = (mf*16 + q*4 + j)*PLS;
        int sww = q*16;
        myP[rowoff + (( 0 + ln) ^ sww)] = f2bf(e0);
        myP[rowoff + ((16 + ln) ^ sww)] = f2bf(e1);
        myP[rowoff + ((32 + ln) ^ sww)] = f2bf(e2);
        myP[rowoff + ((48 + ln) ^ sww)] = f2bf(e3);
      }
    }
#pragma unroll
    for (int kk = 0; kk < 2; kk++) {
      short8 ap[4];
#pragma unroll
      for (int mf = 0; mf < 4; mf++)
        ap[mf] = *(const short8*)&myP[(mf*16 + ln)*PLS + ((kk*32 + q*8) ^ swr)];
      short8 bv[2];
#pragma unroll
      for (int nf2 = 0; nf2 < 2; nf2++) {
        int d = h*32 + nf2*16 + ln;
        int K0 = kk*32 + q*8;
        const unsigned short* vp = vT + ((size_t)b*CH + d)*(HGT*WID)
            + (sy*8 + (K0 >> 3))*WID + sx*8;
        bv[nf2] = *(const short8*)vp;
      }
#pragma unroll
      for (int mf = 0; mf < 4; mf++)
#pragma unroll
        for (int nf2 = 0; nf2 < 2; nf2++)
          facc[mf][nf2] = __builtin_amdgcn_mfma_f32_16x16x32_bf16(
              ap[mf], bv[nf2], facc[mf][nf2], 0, 0, 0);
    }
  }
#pragma unroll
  for (int mf = 0; mf < 4; mf++)
#pragma unroll
    for (int j = 0; j < 4; j++) {
      float l = l_run[mf][j];
      l += __shfl_xor(l, 1);
      l += __shfl_xor(l, 2);
      l += __shfl_xor(l, 4);
      l += __shfl_xor(l, 8);
      float inv = 1.f / l;
      int prow = mf*16 + q*4 + j;
      size_t pg = ((size_t)b*HGT + wy*8 + (prow>>3))*WID + wx*8 + (prow&7);
      o[pg*CH + h*32 + ln]      = f2bf(facc[mf][0][j] * inv);
      o[pg*CH + h*32 + 16 + ln] = f2bf(facc[mf][1][j] * inv);
    }
}

// ---------------------------------------------------------------------------
// K6: o(bf16) += dwconv5x5(v) + lepe_b  — LDS-staged from planar bf16 vT.
// ---------------------------------------------------------------------------
__global__ __launch_bounds__(256) void k_lepe(const unsigned short* __restrict__ vT,
    const float* __restrict__ lw, const float* __restrict__ lb,
    unsigned short* __restrict__ o) {
  __shared__ unsigned short sh[12*60*32];
  int b = blockIdx.y;
  int rg = blockIdx.x >> 2, cg = blockIdx.x & 3;
  int row0 = rg*8, c0 = cg*32;
  int t = threadIdx.x;
  for (int i = t; i < 12*60*32/8; i += 256)
    ((int4*)sh)[i] = make_int4(0,0,0,0);
  __syncthreads();
  for (int i = t; i < 2688; i += 256) {
    int chunk = i % 7, rr = (i/7) % 12, c = i / 84;
    int grow = row0 + rr - 2;
    if ((unsigned)grow < HGT) {
      int4 v = *(const int4*)(vT + ((size_t)(b*CH + c0 + c))*(HGT*WID) + grow*WID + chunk*8);
      union { int4 v4; unsigned short us[8]; } u; u.v4 = v;
#pragma unroll
      for (int j = 0; j < 8; j++)
        sh[(rr*60 + 2 + chunk*8 + j)*32 + c] = u.us[j];
    }
  }
  __syncthreads();
  int c = t & 31, pg = t >> 5;
  float w[25];
#pragma unroll
  for (int i = 0; i < 25; i++) w[i] = lw[(c0 + c)*25 + i];
  float bias = lb[c0 + c];
  const unsigned short* rowp[5];
#pragma unroll
  for (int dy = 0; dy < 5; dy++) rowp[dy] = &sh[((pg + dy)*60)*32 + c];
  float win[5][5];
#pragma unroll
  for (int j = 0; j < 4; j++)
#pragma unroll
    for (int dy = 0; dy < 5; dy++) win[j][dy] = bf2f(rowp[dy][j*32]);
  unsigned short* ob = &o[(((size_t)b*HGT + row0 + pg)*WID)*CH + c0 + c];
#pragma unroll
  for (int col = 0; col < 56; col++) {
    int slot = (col + 4) % 5;
#pragma unroll
    for (int dy = 0; dy < 5; dy++) win[slot][dy] = bf2f(rowp[dy][(col + 4)*32]);
    float s = bias;
#pragma unroll
    for (int dx = 0; dx < 5; dx++) {
      int sl = (col + dx) % 5;
#pragma unroll
      for (int dy = 0; dy < 5; dy++) s += win[sl][dy] * w[dy*5 + dx];
    }
    unsigned short* p = &ob[col*CH];
    *p = f2bf(bf2f(*p) + s);
  }
}

// ---------------------------------------------------------------------------
// K7: xh += o(bf16) @ wo + wo_b  (K=128, N=128) via MFMA.
// ---------------------------------------------------------------------------
__global__ __launch_bounds__(256, 2) void k_wo_mfma(
    const unsigned short* __restrict__ in, const unsigned short* __restrict__ Wt,
    const float* __restrict__ bias, float* __restrict__ xh) {
  __shared__ __align__(16) unsigned short aL[128*136];
  __shared__ __align__(16) unsigned short bL[128*136];
  size_t base = (size_t)blockIdx.x * 128;
  int t = threadIdx.x;
  {
    int r = t >> 1, half = t & 1;
    const int4* src = (const int4*)(in + (base + r)*CH + half*64);
#pragma unroll
    for (int i = 0; i < 8; i++)
      *(int4*)&aL[r*136 + half*64 + i*8] = src[i];
  }
  for (int i = t; i < 2048; i += 256) {
    int row = i >> 4, seg = i & 15;
    *(int4*)&bL[row*136 + seg*8] = *(const int4*)(Wt + (size_t)row*128 + seg*8);
  }
  __syncthreads();
  int wid = t >> 6, lane = t & 63;
  int ln = lane & 15, q = lane >> 4;
  int wr = (wid >> 1)*64, wc = (wid & 1)*64;
  float4v acc[4][4];
#pragma unroll
  for (int a = 0; a < 4; a++)
#pragma unroll
    for (int b = 0; b < 4; b++)
      acc[a][b] = (float4v){0.f, 0.f, 0.f, 0.f};
#pragma unroll
  for (int kk = 0; kk < 4; kk++) {
    int ko = kk*32 + q*8;
    short8 af[4], bf[4];
#pragma unroll
    for (int mf = 0; mf < 4; mf++)
      af[mf] = *(const short8*)&aL[(wr + mf*16 + ln)*136 + ko];
#pragma unroll
    for (int nf = 0; nf < 4; nf++)
      bf[nf] = *(const short8*)&bL[(wc + nf*16 + ln)*136 + ko];
#pragma unroll
    for (int mf = 0; mf < 4; mf++)
#pragma unroll
      for (int nf = 0; nf < 4; nf++)
        acc[mf][nf] = __builtin_amdgcn_mfma_f32_16x16x32_bf16(
            af[mf], bf[nf], acc[mf][nf], 0, 0, 0);
  }
#pragma unroll
  for (int mf = 0; mf < 4; mf++)
#pragma unroll
    for (int nf = 0; nf < 4; nf++) {
      int row = wr + mf*16 + q*4;
      int col = wc + nf*16 + ln;
      float b4 = bias[col];
#pragma unroll
      for (int j = 0; j < 4; j++) {
        float* p = &xh[(base + row + j)*CH + col];
        *p += acc[mf][nf][j] + b4;
      }
    }
}

// ---------------------------------------------------------------------------
// K8: fused MLP, 64-row M-tile (784 blocks, 35 KB LDS -> 4 blocks/CU).
// LN(xh) -> aL; per chunk: acc1 = aL@W1c (B direct from L2), GELU -> cL,
// acc2 += cL@W2c. out(NCHW) = acc2 + b2 + xh. Wave tile 32x64.
// ---------------------------------------------------------------------------
__global__ __launch_bounds__(256, 2) void k_mlp(
    const float* __restrict__ in, const float* __restrict__ g,
    const float* __restrict__ be, const unsigned short* __restrict__ W1t,
    const float* __restrict__ b1, const unsigned short* __restrict__ W2t,
    const float* __restrict__ b2, float* __restrict__ out) {
  __shared__ __align__(16) unsigned short aL[64*136];
  __shared__ __align__(16) unsigned short cL[64*136];
  size_t base = (size_t)blockIdx.x * 64;
  int t = threadIdx.x;
  { // LN + A-stage: 4 threads per row (r = t>>2, qu = t&3 handles 32 ch)
    int r = t >> 2, qu = t & 3;
    const float4* src = (const float4*)(in + (base + r)*CH + qu*32);
    float v[32]; float s = 0.f, ss = 0.f;
#pragma unroll
    for (int i = 0; i < 8; i++) {
      float4 f = src[i];
      v[4*i] = f.x; v[4*i+1] = f.y; v[4*i+2] = f.z; v[4*i+3] = f.w;
      s += f.x + f.y + f.z + f.w;
      ss += f.x*f.x + f.y*f.y + f.z*f.z + f.w*f.w;
    }
    s += __shfl_xor(s, 1); ss += __shfl_xor(ss, 1);
    s += __shfl_xor(s, 2); ss += __shfl_xor(ss, 2);
    float m  = s * (1.f/128.f);
    float var = ss * (1.f/128.f) - m*m;
    float rs = rsqrtf(var + 1e-6f);
    union { unsigned short us[8]; int4 v4; } pk;
#pragma unroll
    for (int c8 = 0; c8 < 4; c8++) {
#pragma unroll
      for (int j = 0; j < 8; j++) {
        int ch = qu*32 + c8*8 + j;
        pk.us[j] = f2bf((v[c8*8 + j] - m) * rs * g[ch] + be[ch]);
      }
      *(int4*)&aL[r*136 + qu*32 + c8*8] = pk.v4;
    }
  }
  __syncthreads();
  int wid = t >> 6, lane = t & 63;
  int ln = lane & 15, q = lane >> 4;
  int wr = (wid >> 1)*32, wc = (wid & 1)*64;
  float4v acc2[2][4];
#pragma unroll
  for (int a = 0; a < 2; a++)
#pragma unroll
    for (int b = 0; b < 4; b++)
      acc2[a][b] = (float4v){0.f, 0.f, 0.f, 0.f};
  for (int chunk = 0; chunk < 3; chunk++) {
    // ---- mlp1 chunk: acc1 = aL @ W1[chunk] ----
    float4v acc1[2][4];
#pragma unroll
    for (int a = 0; a < 2; a++)
#pragma unroll
      for (int b = 0; b < 4; b++)
        acc1[a][b] = (float4v){0.f, 0.f, 0.f, 0.f};
#pragma unroll
    for (int kk = 0; kk < 4; kk++) {
      int ko = kk*32 + q*8;
      short8 af[2], bf[4];
#pragma unroll
      for (int mf = 0; mf < 2; mf++)
        af[mf] = *(const short8*)&aL[(wr + mf*16 + ln)*136 + ko];
#pragma unroll
      for (int nf = 0; nf < 4; nf++)
        bf[nf] = *(const short8*)&W1t[(size_t)(chunk*128 + wc + nf*16 + ln)*128 + ko];
#pragma unroll
      for (int mf = 0; mf < 2; mf++)
#pragma unroll
        for (int nf = 0; nf < 4; nf++)
          acc1[mf][nf] = __builtin_amdgcn_mfma_f32_16x16x32_bf16(
              af[mf], bf[nf], acc1[mf][nf], 0, 0, 0);
    }
    // ---- GELU -> cL ----
    __syncthreads();   // previous chunk's cL reads complete
#pragma unroll
    for (int mf = 0; mf < 2; mf++)
#pragma unroll
      for (int nf = 0; nf < 4; nf++) {
        int row = wr + mf*16 + q*4;
        int col = wc + nf*16 + ln;
        float b4 = b1[chunk*128 + col];
#pragma unroll
        for (int j = 0; j < 4; j++) {
          float vv = acc1[mf][nf][j] + b4;
          vv = 0.5f * vv * (1.f + erff(vv * 0.70710678118654752f));
          cL[(row + j)*136 + col] = f2bf(vv);
        }
      }
    __syncthreads();
    // ---- mlp2 partial: acc2 += cL @ W2[:, chunk] ----
#pragma unroll
    for (int kk = 0; kk < 4; kk++) {
      int ko = kk*32 + q*8;
      short8 af[2], bf[4];
#pragma unroll
      for (int mf = 0; mf < 2; mf++)
        af[mf] = *(const short8*)&cL[(wr + mf*16 + ln)*136 + ko];
#pragma unroll
      for (int nf = 0; nf < 4; nf++)
        bf[nf] = *(const short8*)&W2t[(size_t)(wc + nf*16 + ln)*NQKV + chunk*128 + ko];
#pragma unroll
      for (int mf = 0; mf < 2; mf++)
#pragma unroll
        for (int nf = 0; nf < 4; nf++)
          acc2[mf][nf] = __builtin_amdgcn_mfma_f32_16x16x32_bf16(
              af[mf], bf[nf], acc2[mf][nf], 0, 0, 0);
    }
  }
#pragma unroll
  for (int mf = 0; mf < 2; mf++)
#pragma unroll
    for (int nf = 0; nf < 4; nf++) {
      int row = wr + mf*16 + q*4;
      int col = wc + nf*16 + ln;
      float b4 = b2[col];
#pragma unroll
      for (int j = 0; j < 4; j++) {
        size_t pixel = base + row + j;
        int b = (int)(pixel / (HGT*WID));
        int sp = (int)(pixel % (HGT*WID));
        out[((size_t)b*CH + col)*(HGT*WID) + sp] =
            acc2[mf][nf][j] + b4 + in[pixel*CH + col];
      }
    }
}

// ---------------------------------------------------------------------------
extern "C" void kernel_launch(void* const* d_in, const int* in_sizes, int n_in,
                              void* d_out, int out_size, void* d_ws, size_t ws_size,
                              hipStream_t stream) {
  const float* x      = (const float*)d_in[0];
  const float* pos_w  = (const float*)d_in[1];
  const float* pos_b  = (const float*)d_in[2];
  const float* ln1_g  = (const float*)d_in[3];
  const float* ln1_b  = (const float*)d_in[4];
  const float* qkv_w  = (const float*)d_in[5];
  const float* qkv_b  = (const float*)d_in[6];
  const float* lepe_w = (const float*)d_in[7];
  const float* lepe_b = (const float*)d_in[8];
  const float* wo_w   = (const float*)d_in[9];
  const float* wo_b   = (const float*)d_in[10];
  const float* ln2_g  = (const float*)d_in[11];
  const float* ln2_b  = (const float*)d_in[12];
  const float* mlp_w1 = (const float*)d_in[13];
  const float* mlp_b1 = (const float*)d_in[14];
  const float* mlp_w2 = (const float*)d_in[15];
  const float* mlp_b2 = (const float*)d_in[16];

  float* ws   = (float*)d_ws;
  float* xh   = ws;                          // NPIX*128 f32
  float* o_slot = xh + (size_t)NPIX*CH;      // NPIX*128 slot (bf16 used)
  unsigned short* obf = (unsigned short*)o_slot;
  float* qwin = o_slot + (size_t)NPIX*CH;    // 784*128
  float* kwin = qwin + (size_t)BATCH*P2*128; // 784*128
  int*   idx  = (int*)(kwin + (size_t)BATCH*P2*128); // 784*4
  unsigned short* Wq = (unsigned short*)(idx + BATCH*P2*TOPK); // 384*128
  unsigned short* Wo = Wq + 384*128;         // 128*128
  unsigned short* W1 = Wo + 128*128;         // 384*128
  unsigned short* W2 = W1 + 384*128;         // 128*384
  unsigned short* vT = W2 + 128*384;         // NPIX*128 bf16
  unsigned short* qW = vT + (size_t)NPIX*CH; // NPIX*128 bf16
  unsigned short* kW = qW + (size_t)NPIX*CH; // NPIX*128 bf16

  k_prep<<<1024, 128, 0, stream>>>(qkv_w, wo_w, mlp_w1, mlp_w2, Wq, Wo, W1, W2);
  k_posconv<<<dim3(28, BATCH), 256, 0, stream>>>(x, pos_w, pos_b, xh);
  k_route<<<BATCH*P2, 256, 0, stream>>>(xh, ln1_g, ln1_b, qkv_w, qkv_b, qwin, kwin);
  k_topk<<<BATCH*P2, 256, 0, stream>>>(qwin, kwin, idx);
  k_qkv_gemm<<<NPIX/128, 256, 0, stream>>>(xh, ln1_g, ln1_b, Wq, qkv_b, qW, kW, vT);
  k_attn_mfma<<<BATCH*P2, 256, 0, stream>>>(qW, kW, vT, idx, obf);
  k_lepe<<<dim3(28, BATCH), 256, 0, stream>>>(vT, lepe_w, lepe_b, obf);
  k_wo_mfma<<<NPIX/128, 256, 0, stream>>>(obf, Wo, wo_b, xh);
  k_mlp<<<NPIX/64, 256, 0, stream>>>(xh, ln2_g, ln2_b, W1, mlp_b1, W2, mlp_b2,
                                     (float*)d_out);
}

// Round 14
// 317.763 us; speedup vs baseline: 1.0744x; 1.0744x over previous
//
#include <hip/hip_runtime.h>
#include <math.h>

#define BATCH 16
#define CH    128
#define HGT   56
#define WID   56
#define NPIX  (BATCH*HGT*WID)   // 50176
#define NQKV  384
#define NWIN  7
#define P2    49
#define TOPK  4
#define ATT_SCALE 0.088388347648318447f   // 128^-0.5

typedef __attribute__((ext_vector_type(8))) short short8;
typedef __attribute__((ext_vector_type(4))) short short4v;
typedef __attribute__((ext_vector_type(4))) float float4v;

static __device__ __forceinline__ unsigned short f2bf(float f) {
  unsigned u = __float_as_uint(f);
  u += 0x7fffu + ((u >> 16) & 1u);   // round-to-nearest-even
  return (unsigned short)(u >> 16);
}
static __device__ __forceinline__ float bf2f(unsigned short u) {
  return __uint_as_float((unsigned)u << 16);
}

// ---------------------------------------------------------------------------
// K0: weight prep — convert to bf16 and transpose to [N][K] layout.
// ---------------------------------------------------------------------------
__global__ __launch_bounds__(128) void k_prep(
    const float* __restrict__ qkv_w, const float* __restrict__ wo_w,
    const float* __restrict__ mlp_w1, const float* __restrict__ mlp_w2,
    unsigned short* __restrict__ Wq, unsigned short* __restrict__ Wo,
    unsigned short* __restrict__ W1, unsigned short* __restrict__ W2) {
  int bx = blockIdx.x, t = threadIdx.x;
  if (bx < 384) {
    int n = bx;
    Wq[n*128 + t] = f2bf(qkv_w[(size_t)t*384 + n]);
  } else if (bx < 512) {
    int n = bx - 384;
    Wo[n*128 + t] = f2bf(wo_w[(size_t)t*128 + n]);
  } else if (bx < 896) {
    int n = bx - 512;
    W1[n*128 + t] = f2bf(mlp_w1[(size_t)t*384 + n]);
  } else {
    int n = bx - 896;
    for (int k = t; k < 384; k += 128)
      W2[n*384 + k] = f2bf(mlp_w2[(size_t)k*128 + n]);
  }
}

// ---------------------------------------------------------------------------
// K1: x(NCHW) -> xh(NHWC) = x + dwconv3x3(x).  LDS-staged transpose.
// ---------------------------------------------------------------------------
__global__ __launch_bounds__(256) void k_posconv(const float* __restrict__ x,
    const float* __restrict__ pw, const float* __restrict__ pb,
    float* __restrict__ xh) {
  __shared__ float sh[10*58*32];
  int b = blockIdx.y;
  int rg = blockIdx.x >> 2, cg = blockIdx.x & 3;
  int row0 = rg*8, c0 = cg*32;
  int t = threadIdx.x;
  for (int i = t; i < 10*58*32/4; i += 256)
    ((int4*)sh)[i] = make_int4(0,0,0,0);
  __syncthreads();
  for (int i = t; i < 4480; i += 256) {
    int c = i & 31, chunk = (i >> 5) % 14, rr = i / 448;
    int grow = row0 + rr - 1;
    if ((unsigned)grow < HGT) {
      float4 v = *(const float4*)(x + ((size_t)(b*CH + c0 + c))*(HGT*WID)
                                  + grow*WID + chunk*4);
      float* d = &sh[(rr*58 + 1 + chunk*4)*32 + c];
      d[0] = v.x; d[32] = v.y; d[64] = v.z; d[96] = v.w;
    }
  }
  __syncthreads();
  int c = t & 31, pg = t >> 5;
  float w[9];
#pragma unroll
  for (int i = 0; i < 9; i++) w[i] = pw[(c0 + c)*9 + i];
  float bias = pb[c0 + c];
  const float* rowp[3];
#pragma unroll
  for (int dy = 0; dy < 3; dy++) rowp[dy] = &sh[((pg + dy)*58)*32 + c];
  float win[3][3];
#pragma unroll
  for (int j = 0; j < 2; j++)
#pragma unroll
    for (int dy = 0; dy < 3; dy++) win[j][dy] = rowp[dy][j*32];
  float* ob = &xh[(((size_t)b*HGT + row0 + pg)*WID)*CH + c0 + c];
#pragma unroll
  for (int col = 0; col < 56; col++) {
    int slot = (col + 2) % 3;
#pragma unroll
    for (int dy = 0; dy < 3; dy++) win[slot][dy] = rowp[dy][(col + 2)*32];
    float s = bias + win[(col + 1) % 3][1];
#pragma unroll
    for (int dx = 0; dx < 3; dx++) {
      int sl = (col + dx) % 3;
#pragma unroll
      for (int dy = 0; dy < 3; dy++) s += win[sl][dy] * w[dy*3 + dx];
    }
    ob[col*CH] = s;
  }
}

// ---------------------------------------------------------------------------
// K_route: per window, LN(xh) -> window-mean ym -> qwin/kwin = ym@W + b.
// ---------------------------------------------------------------------------
__global__ __launch_bounds__(256) void k_route(const float* __restrict__ xh,
    const float* __restrict__ g, const float* __restrict__ be,
    const float* __restrict__ qkv_w, const float* __restrict__ qkv_b,
    float* __restrict__ qwin, float* __restrict__ kwin) {
  __shared__ float yt[128*68];
  __shared__ float ym[128];
  int bp = blockIdx.x; int b = bp / P2, p = bp % P2;
  int wy = p / NWIN, wx = p % NWIN;
  int t = threadIdx.x;
  int pl = t >> 2, qu = t & 3;
  {
    int hg = wy*8 + (pl >> 3), wg = wx*8 + (pl & 7);
    const float4* src = (const float4*)(xh + (((size_t)b*HGT + hg)*WID + wg)*CH + qu*32);
    float v[32]; float s = 0.f, ss = 0.f;
#pragma unroll
    for (int i = 0; i < 8; i++) {
      float4 f = src[i];
      v[4*i] = f.x; v[4*i+1] = f.y; v[4*i+2] = f.z; v[4*i+3] = f.w;
      s += f.x + f.y + f.z + f.w;
      ss += f.x*f.x + f.y*f.y + f.z*f.z + f.w*f.w;
    }
    s += __shfl_xor(s, 1); ss += __shfl_xor(ss, 1);
    s += __shfl_xor(s, 2); ss += __shfl_xor(ss, 2);
    float m  = s * (1.f/128.f);
    float var = ss * (1.f/128.f) - m*m;
    float rs = rsqrtf(var + 1e-6f);
#pragma unroll
    for (int i = 0; i < 32; i++) {
      int ch = qu*32 + i;
      yt[ch*68 + pl] = (v[i] - m) * rs * g[ch] + be[ch];
    }
  }
  __syncthreads();
  if (t < 128) {
    const float4* col = (const float4*)&yt[t*68];
    float4 a = make_float4(0.f,0.f,0.f,0.f);
#pragma unroll
    for (int i = 0; i < 16; i++) {
      float4 f = col[i];
      a.x += f.x; a.y += f.y; a.z += f.z; a.w += f.w;
    }
    ym[t] = (a.x + a.y + a.z + a.w) * (1.f/64.f);
  }
  __syncthreads();
  {
    int n = t;
    float s = qkv_b[n];
#pragma unroll 4
    for (int c = 0; c < 128; c++) s += ym[c] * qkv_w[(size_t)c*NQKV + n];
    if (n < 128) qwin[(size_t)bp*128 + n] = s;
    else         kwin[(size_t)bp*128 + n - 128] = s;
  }
}

// ---------------------------------------------------------------------------
// K4: routing logits + top-4.
// ---------------------------------------------------------------------------
__global__ __launch_bounds__(256) void k_topk(const float* __restrict__ qwin,
    const float* __restrict__ kwin, int* __restrict__ idx) {
  __shared__ float logits[64];
  int bp = blockIdx.x; int b = bp / P2;
  int t = threadIdx.x;
  int key = t >> 2, qu = t & 3;
  float s = 0.f;
  if (key < P2) {
    const float4* qp = (const float4*)(qwin + (size_t)bp*128 + qu*32);
    const float4* kp = (const float4*)(kwin + ((size_t)b*P2 + key)*128 + qu*32);
#pragma unroll
    for (int i = 0; i < 8; i++) {
      float4 qv = qp[i], kv = kp[i];
      s += qv.x*kv.x + qv.y*kv.y + qv.z*kv.z + qv.w*kv.w;
    }
  }
  s += __shfl_xor(s, 1);
  s += __shfl_xor(s, 2);
  if (qu == 0 && key < P2) logits[key] = s;
  __syncthreads();
  if (t == 0) {
    unsigned long long used = 0ULL;
    for (int tt = 0; tt < TOPK; tt++) {
      float best = -1e30f; int bi = 0;
      for (int q = 0; q < P2; q++) {
        bool ok = !((used >> q) & 1ULL);
        float lv = logits[q];
        if (ok && lv > best) { best = lv; bi = q; }
      }
      used |= 1ULL << bi;
      idx[(size_t)bp*TOPK + tt] = bi;
    }
  }
}

// ---------------------------------------------------------------------------
// K_qkv: LN + MFMA GEMM (aL + bL in LDS, (256,2)).
// bf16 epilogues -> qW (windowed, *scale), kW, vT (planar via aL restage).
// ---------------------------------------------------------------------------
__global__ __launch_bounds__(256, 2) void k_qkv_gemm(
    const float* __restrict__ in, const float* __restrict__ g,
    const float* __restrict__ be, const unsigned short* __restrict__ Wt,
    const float* __restrict__ bias,
    unsigned short* __restrict__ qW, unsigned short* __restrict__ kW,
    unsigned short* __restrict__ vT) {
  __shared__ __align__(16) unsigned short aL[128*136];
  __shared__ __align__(16) unsigned short bL[128*136];
  int base = blockIdx.x * 128;
  int t = threadIdx.x;
  { // ---- LN + A-stage ----
    int r = t >> 1, half = t & 1;
    const float4* src = (const float4*)(in + (size_t)(base + r)*CH + half*64);
    float v[64];
    float s = 0.f, ss = 0.f;
#pragma unroll
    for (int i = 0; i < 16; i++) {
      float4 f = src[i];
      v[4*i] = f.x; v[4*i+1] = f.y; v[4*i+2] = f.z; v[4*i+3] = f.w;
      s += f.x + f.y + f.z + f.w;
      ss += f.x*f.x + f.y*f.y + f.z*f.z + f.w*f.w;
    }
    s += __shfl_xor(s, 1); ss += __shfl_xor(ss, 1);
    float m  = s * (1.f/128.f);
    float var = ss * (1.f/128.f) - m*m;
    float rs = rsqrtf(var + 1e-6f);
    union { unsigned short us[8]; int4 v4; } pk;
#pragma unroll
    for (int c8 = 0; c8 < 8; c8++) {
#pragma unroll
      for (int j = 0; j < 8; j++) {
        int ch = half*64 + c8*8 + j;
        pk.us[j] = f2bf((v[c8*8 + j] - m) * rs * g[ch] + be[ch]);
      }
      *(int4*)&aL[r*136 + half*64 + c8*8] = pk.v4;
    }
  }
  int wid = t >> 6, lane = t & 63;
  int ln = lane & 15, q = lane >> 4;
  int wr = (wid >> 1)*64, wc = (wid & 1)*64;
  for (int chunk = 0; chunk < 3; chunk++) {
    if (chunk) __syncthreads();
    for (int i = t; i < 2048; i += 256) {
      int row = i >> 4, seg = i & 15;
      *(int4*)&bL[row*136 + seg*8] =
          *(const int4*)(Wt + (size_t)(chunk*128 + row)*128 + seg*8);
    }
    __syncthreads();
    float4v acc[4][4];
#pragma unroll
    for (int a = 0; a < 4; a++)
#pragma unroll
      for (int b2 = 0; b2 < 4; b2++)
        acc[a][b2] = (float4v){0.f, 0.f, 0.f, 0.f};
#pragma unroll
    for (int kk = 0; kk < 4; kk++) {
      int ko = kk*32 + q*8;
      short8 af[4], bf[4];
#pragma unroll
      for (int mf = 0; mf < 4; mf++)
        af[mf] = *(const short8*)&aL[(wr + mf*16 + ln)*136 + ko];
#pragma unroll
      for (int nf = 0; nf < 4; nf++)
        bf[nf] = *(const short8*)&bL[(wc + nf*16 + ln)*136 + ko];
#pragma unroll
      for (int mf = 0; mf < 4; mf++)
#pragma unroll
        for (int nf = 0; nf < 4; nf++)
          acc[mf][nf] = __builtin_amdgcn_mfma_f32_16x16x32_bf16(
              af[mf], bf[nf], acc[mf][nf], 0, 0, 0);
    }
    if (chunk < 2) {
      unsigned short* dst = chunk ? kW : qW;
      float sc = chunk ? 1.f : ATT_SCALE;
#pragma unroll
      for (int mf = 0; mf < 4; mf++) {
#pragma unroll
        for (int j = 0; j < 4; j++) {
          int pg = base + wr + mf*16 + q*4 + j;
          int b  = pg / 3136, sp = pg - b*3136;
          int hh = sp / 56, ww = sp - hh*56;
          int p  = (hh >> 3)*NWIN + (ww >> 3);
          int ploc = (hh & 7)*8 + (ww & 7);
          size_t rb = ((size_t)(b*P2 + p)*64 + ploc)*128;
#pragma unroll
          for (int nf = 0; nf < 4; nf++) {
            int col = wc + nf*16 + ln;
            dst[rb + col] = f2bf((acc[mf][nf][j] + bias[chunk*128 + col])*sc);
          }
        }
      }
    } else {
      __syncthreads();   // all aL reads done -> reuse as v staging
#pragma unroll
      for (int mf = 0; mf < 4; mf++)
#pragma unroll
        for (int nf = 0; nf < 4; nf++) {
          int row = wr + mf*16 + q*4;
          int col = wc + nf*16 + ln;
          float b4 = bias[256 + col];
          short4v pk;
#pragma unroll
          for (int j = 0; j < 4; j++) pk[j] = (short)f2bf(acc[mf][nf][j] + b4);
          *(short4v*)&aL[col*136 + row] = pk;
        }
      __syncthreads();
      int c = t >> 1, half = t & 1;
#pragma unroll
      for (int g8 = 0; g8 < 8; g8++) {
        int pg0 = base + half*64 + g8*8;
        int b = pg0 / 3136, sp = pg0 - b*3136;
        *(int4*)(vT + ((size_t)(b*CH + c))*3136 + sp) =
            *(int4*)&aL[c*136 + half*64 + g8*8];
      }
    }
  }
}

// ---------------------------------------------------------------------------
// K5: MFMA attention, no-max softmax, deferred row-sum, XCD-local per image.
// Output o bf16.
// ---------------------------------------------------------------------------
#define PLS 72
__global__ __launch_bounds__(256) void k_attn_mfma(
    const unsigned short* __restrict__ qW, const unsigned short* __restrict__ kW,
    const unsigned short* __restrict__ vT, const int* __restrict__ idx,
    unsigned short* __restrict__ o) {
  __shared__ unsigned short pL[4][64*PLS];
  int bx = blockIdx.x;
  int b = bx & 15, p = bx >> 4;
  int bp = b*P2 + p;
  int wy = p / NWIN, wx = p % NWIN;
  int h = threadIdx.x >> 6, lane = threadIdx.x & 63;
  int ln = lane & 15, q = lane >> 4;

  short8 aq[4];
#pragma unroll
  for (int mf = 0; mf < 4; mf++)
    aq[mf] = *(const short8*)&qW[((size_t)bp*64 + mf*16 + ln)*128 + h*32 + q*8];

  int4 widx = *(const int4*)&idx[(size_t)bp*TOPK];
  int wins[4] = {widx.x, widx.y, widx.z, widx.w};

  float l_run[4][4];
  float4v facc[4][2];
#pragma unroll
  for (int mf = 0; mf < 4; mf++) {
#pragma unroll
    for (int j = 0; j < 4; j++) l_run[mf][j] = 0.f;
    facc[mf][0] = (float4v){0.f,0.f,0.f,0.f};
    facc[mf][1] = (float4v){0.f,0.f,0.f,0.f};
  }

  unsigned short* myP = &pL[h][0];
  int swr = ((ln >> 2) & 3) * 16;

  for (int r = 0; r < TOPK; r++) {
    int win = wins[r];
    int sy = win / NWIN, sx = win % NWIN;
    short8 bk[4];
#pragma unroll
    for (int nf = 0; nf < 4; nf++)
      bk[nf] = *(const short8*)&kW[(((size_t)b*P2 + win)*64 + nf*16 + ln)*128 + h*32 + q*8];
    float4v sacc[4][4];
#pragma unroll
    for (int mf = 0; mf < 4; mf++)
#pragma unroll
      for (int nf = 0; nf < 4; nf++)
        sacc[mf][nf] = (float4v){0.f,0.f,0.f,0.f};
#pragma unroll
    for (int mf = 0; mf < 4; mf++)
#pragma unroll
      for (int nf = 0; nf < 4; nf++)
        sacc[mf][nf] = __builtin_amdgcn_mfma_f32_16x16x32_bf16(
            aq[mf], bk[nf], sacc[mf][nf], 0, 0, 0);
#pragma unroll
    for (int mf = 0; mf < 4; mf++) {
#pragma unroll
      for (int j = 0; j < 4; j++) {
        float e0 = __expf(sacc[mf][0][j]);
        float e1 = __expf(sacc[mf][1][j]);
        float e2 = __expf(sacc[mf][2][j]);
        float e3 = __expf(sacc[mf][3][j]);
        l_run[mf][j] += (e0 + e1) + (e2 + e3);
        int rowoff = (mf*16 + q*4 + j)*PLS;
        int sww = q*16;
        myP[rowoff + (( 0 + ln) ^ sww)] = f2bf(e0);
        myP[rowoff + ((16 + ln) ^ sww)] = f2bf(e1);
        myP[rowoff + ((32 + ln) ^ sww)] = f2bf(e2);
        myP[rowoff + ((48 + ln) ^ sww)] = f2bf(e3);
      }
    }
#pragma unroll
    for (int kk = 0; kk < 2; kk++) {
      short8 ap[4];
#pragma unroll
      for (int mf = 0; mf < 4; mf++)
        ap[mf] = *(const short8*)&myP[(mf*16 + ln)*PLS + ((kk*32 + q*8) ^ swr)];
      short8 bv[2];
#pragma unroll
      for (int nf2 = 0; nf2 < 2; nf2++) {
        int d = h*32 + nf2*16 + ln;
        int K0 = kk*32 + q*8;
        const unsigned short* vp = vT + ((size_t)b*CH + d)*(HGT*WID)
            + (sy*8 + (K0 >> 3))*WID + sx*8;
        bv[nf2] = *(const short8*)vp;
      }
#pragma unroll
      for (int mf = 0; mf < 4; mf++)
#pragma unroll
        for (int nf2 = 0; nf2 < 2; nf2++)
          facc[mf][nf2] = __builtin_amdgcn_mfma_f32_16x16x32_bf16(
              ap[mf], bv[nf2], facc[mf][nf2], 0, 0, 0);
    }
  }
#pragma unroll
  for (int mf = 0; mf < 4; mf++)
#pragma unroll
    for (int j = 0; j < 4; j++) {
      float l = l_run[mf][j];
      l += __shfl_xor(l, 1);
      l += __shfl_xor(l, 2);
      l += __shfl_xor(l, 4);
      l += __shfl_xor(l, 8);
      float inv = 1.f / l;
      int prow = mf*16 + q*4 + j;
      size_t pg = ((size_t)b*HGT + wy*8 + (prow>>3))*WID + wx*8 + (prow&7);
      o[pg*CH + h*32 + ln]      = f2bf(facc[mf][0][j] * inv);
      o[pg*CH + h*32 + 16 + ln] = f2bf(facc[mf][1][j] * inv);
    }
}

// ---------------------------------------------------------------------------
// K6: o(bf16) += dwconv5x5(v) + lepe_b  — LDS-staged from planar bf16 vT.
// ---------------------------------------------------------------------------
__global__ __launch_bounds__(256) void k_lepe(const unsigned short* __restrict__ vT,
    const float* __restrict__ lw, const float* __restrict__ lb,
    unsigned short* __restrict__ o) {
  __shared__ unsigned short sh[12*60*32];
  int b = blockIdx.y;
  int rg = blockIdx.x >> 2, cg = blockIdx.x & 3;
  int row0 = rg*8, c0 = cg*32;
  int t = threadIdx.x;
  for (int i = t; i < 12*60*32/8; i += 256)
    ((int4*)sh)[i] = make_int4(0,0,0,0);
  __syncthreads();
  for (int i = t; i < 2688; i += 256) {
    int chunk = i % 7, rr = (i/7) % 12, c = i / 84;
    int grow = row0 + rr - 2;
    if ((unsigned)grow < HGT) {
      int4 v = *(const int4*)(vT + ((size_t)(b*CH + c0 + c))*(HGT*WID) + grow*WID + chunk*8);
      union { int4 v4; unsigned short us[8]; } u; u.v4 = v;
#pragma unroll
      for (int j = 0; j < 8; j++)
        sh[(rr*60 + 2 + chunk*8 + j)*32 + c] = u.us[j];
    }
  }
  __syncthreads();
  int c = t & 31, pg = t >> 5;
  float w[25];
#pragma unroll
  for (int i = 0; i < 25; i++) w[i] = lw[(c0 + c)*25 + i];
  float bias = lb[c0 + c];
  const unsigned short* rowp[5];
#pragma unroll
  for (int dy = 0; dy < 5; dy++) rowp[dy] = &sh[((pg + dy)*60)*32 + c];
  float win[5][5];
#pragma unroll
  for (int j = 0; j < 4; j++)
#pragma unroll
    for (int dy = 0; dy < 5; dy++) win[j][dy] = bf2f(rowp[dy][j*32]);
  unsigned short* ob = &o[(((size_t)b*HGT + row0 + pg)*WID)*CH + c0 + c];
#pragma unroll
  for (int col = 0; col < 56; col++) {
    int slot = (col + 4) % 5;
#pragma unroll
    for (int dy = 0; dy < 5; dy++) win[slot][dy] = bf2f(rowp[dy][(col + 4)*32]);
    float s = bias;
#pragma unroll
    for (int dx = 0; dx < 5; dx++) {
      int sl = (col + dx) % 5;
#pragma unroll
      for (int dy = 0; dy < 5; dy++) s += win[sl][dy] * w[dy*5 + dx];
    }
    unsigned short* p = &ob[col*CH];
    *p = f2bf(bf2f(*p) + s);
  }
}

// ---------------------------------------------------------------------------
// K7: xh += o(bf16) @ wo + wo_b  (K=128, N=128) via MFMA.
// ---------------------------------------------------------------------------
__global__ __launch_bounds__(256, 2) void k_wo_mfma(
    const unsigned short* __restrict__ in, const unsigned short* __restrict__ Wt,
    const float* __restrict__ bias, float* __restrict__ xh) {
  __shared__ __align__(16) unsigned short aL[128*136];
  __shared__ __align__(16) unsigned short bL[128*136];
  size_t base = (size_t)blockIdx.x * 128;
  int t = threadIdx.x;
  {
    int r = t >> 1, half = t & 1;
    const int4* src = (const int4*)(in + (base + r)*CH + half*64);
#pragma unroll
    for (int i = 0; i < 8; i++)
      *(int4*)&aL[r*136 + half*64 + i*8] = src[i];
  }
  for (int i = t; i < 2048; i += 256) {
    int row = i >> 4, seg = i & 15;
    *(int4*)&bL[row*136 + seg*8] = *(const int4*)(Wt + (size_t)row*128 + seg*8);
  }
  __syncthreads();
  int wid = t >> 6, lane = t & 63;
  int ln = lane & 15, q = lane >> 4;
  int wr = (wid >> 1)*64, wc = (wid & 1)*64;
  float4v acc[4][4];
#pragma unroll
  for (int a = 0; a < 4; a++)
#pragma unroll
    for (int b = 0; b < 4; b++)
      acc[a][b] = (float4v){0.f, 0.f, 0.f, 0.f};
#pragma unroll
  for (int kk = 0; kk < 4; kk++) {
    int ko = kk*32 + q*8;
    short8 af[4], bf[4];
#pragma unroll
    for (int mf = 0; mf < 4; mf++)
      af[mf] = *(const short8*)&aL[(wr + mf*16 + ln)*136 + ko];
#pragma unroll
    for (int nf = 0; nf < 4; nf++)
      bf[nf] = *(const short8*)&bL[(wc + nf*16 + ln)*136 + ko];
#pragma unroll
    for (int mf = 0; mf < 4; mf++)
#pragma unroll
      for (int nf = 0; nf < 4; nf++)
        acc[mf][nf] = __builtin_amdgcn_mfma_f32_16x16x32_bf16(
            af[mf], bf[nf], acc[mf][nf], 0, 0, 0);
  }
#pragma unroll
  for (int mf = 0; mf < 4; mf++)
#pragma unroll
    for (int nf = 0; nf < 4; nf++) {
      int row = wr + mf*16 + q*4;
      int col = wc + nf*16 + ln;
      float b4 = bias[col];
#pragma unroll
      for (int j = 0; j < 4; j++) {
        float* p = &xh[(base + row + j)*CH + col];
        *p += acc[mf][nf][j] + b4;
      }
    }
}

// ---------------------------------------------------------------------------
// K8: fused MLP (round-12 proven version, 128-row M-tile, (256,2)):
// LN(xh) -> aL; per chunk: acc1 = aL@W1c (B direct from L2), GELU -> cL,
// acc2 += cL@W2c. out(NCHW) = acc2 + b2 + xh. No hid intermediate.
// ---------------------------------------------------------------------------
__global__ __launch_bounds__(256, 2) void k_mlp(
    const float* __restrict__ in, const float* __restrict__ g,
    const float* __restrict__ be, const unsigned short* __restrict__ W1t,
    const float* __restrict__ b1, const unsigned short* __restrict__ W2t,
    const float* __restrict__ b2, float* __restrict__ out) {
  __shared__ __align__(16) unsigned short aL[128*136];
  __shared__ __align__(16) unsigned short cL[128*136];
  size_t base = (size_t)blockIdx.x * 128;
  int t = threadIdx.x;
  { // LN + A-stage
    int r = t >> 1, half = t & 1;
    const float4* src = (const float4*)(in + (base + r)*CH + half*64);
    float v[64];
    float s = 0.f, ss = 0.f;
#pragma unroll
    for (int i = 0; i < 16; i++) {
      float4 f = src[i];
      v[4*i] = f.x; v[4*i+1] = f.y; v[4*i+2] = f.z; v[4*i+3] = f.w;
      s += f.x + f.y + f.z + f.w;
      ss += f.x*f.x + f.y*f.y + f.z*f.z + f.w*f.w;
    }
    s += __shfl_xor(s, 1); ss += __shfl_xor(ss, 1);
    float m  = s * (1.f/128.f);
    float var = ss * (1.f/128.f) - m*m;
    float rs = rsqrtf(var + 1e-6f);
    union { unsigned short us[8]; int4 v4; } pk;
#pragma unroll
    for (int c8 = 0; c8 < 8; c8++) {
#pragma unroll
      for (int j = 0; j < 8; j++) {
        int ch = half*64 + c8*8 + j;
        pk.us[j] = f2bf((v[c8*8 + j] - m) * rs * g[ch] + be[ch]);
      }
      *(int4*)&aL[r*136 + half*64 + c8*8] = pk.v4;
    }
  }
  __syncthreads();
  int wid = t >> 6, lane = t & 63;
  int ln = lane & 15, q = lane >> 4;
  int wr = (wid >> 1)*64, wc = (wid & 1)*64;
  float4v acc2[4][4];
#pragma unroll
  for (int a = 0; a < 4; a++)
#pragma unroll
    for (int b = 0; b < 4; b++)
      acc2[a][b] = (float4v){0.f, 0.f, 0.f, 0.f};
  for (int chunk = 0; chunk < 3; chunk++) {
    // ---- mlp1 chunk: acc1 = aL @ W1[chunk] (B direct from global/L2) ----
    float4v acc1[4][4];
#pragma unroll
    for (int a = 0; a < 4; a++)
#pragma unroll
      for (int b = 0; b < 4; b++)
        acc1[a][b] = (float4v){0.f, 0.f, 0.f, 0.f};
#pragma unroll
    for (int kk = 0; kk < 4; kk++) {
      int ko = kk*32 + q*8;
      short8 af[4], bf[4];
#pragma unroll
      for (int mf = 0; mf < 4; mf++)
        af[mf] = *(const short8*)&aL[(wr + mf*16 + ln)*136 + ko];
#pragma unroll
      for (int nf = 0; nf < 4; nf++)
        bf[nf] = *(const short8*)&W1t[(size_t)(chunk*128 + wc + nf*16 + ln)*128 + ko];
#pragma unroll
      for (int mf = 0; mf < 4; mf++)
#pragma unroll
        for (int nf = 0; nf < 4; nf++)
          acc1[mf][nf] = __builtin_amdgcn_mfma_f32_16x16x32_bf16(
              af[mf], bf[nf], acc1[mf][nf], 0, 0, 0);
    }
    // ---- GELU -> cL (hid chunk, row-major bf16) ----
    __syncthreads();   // previous chunk's cL reads complete
#pragma unroll
    for (int mf = 0; mf < 4; mf++)
#pragma unroll
      for (int nf = 0; nf < 4; nf++) {
        int row = wr + mf*16 + q*4;
        int col = wc + nf*16 + ln;
        float b4 = b1[chunk*128 + col];
#pragma unroll
        for (int j = 0; j < 4; j++) {
          float vv = acc1[mf][nf][j] + b4;
          vv = 0.5f * vv * (1.f + erff(vv * 0.70710678118654752f));
          cL[(row + j)*136 + col] = f2bf(vv);
        }
      }
    __syncthreads();
    // ---- mlp2 partial: acc2 += cL @ W2[:, chunk] ----
#pragma unroll
    for (int kk = 0; kk < 4; kk++) {
      int ko = kk*32 + q*8;
      short8 af[4], bf[4];
#pragma unroll
      for (int mf = 0; mf < 4; mf++)
        af[mf] = *(const short8*)&cL[(wr + mf*16 + ln)*136 + ko];
#pragma unroll
      for (int nf = 0; nf < 4; nf++)
        bf[nf] = *(const short8*)&W2t[(size_t)(wc + nf*16 + ln)*NQKV + chunk*128 + ko];
#pragma unroll
      for (int mf = 0; mf < 4; mf++)
#pragma unroll
        for (int nf = 0; nf < 4; nf++)
          acc2[mf][nf] = __builtin_amdgcn_mfma_f32_16x16x32_bf16(
              af[mf], bf[nf], acc2[mf][nf], 0, 0, 0);
    }
  }
#pragma unroll
  for (int mf = 0; mf < 4; mf++)
#pragma unroll
    for (int nf = 0; nf < 4; nf++) {
      int row = wr + mf*16 + q*4;
      int col = wc + nf*16 + ln;
      float b4 = b2[col];
#pragma unroll
      for (int j = 0; j < 4; j++) {
        size_t pixel = base + row + j;
        int b = (int)(pixel / (HGT*WID));
        int sp = (int)(pixel % (HGT*WID));
        out[((size_t)b*CH + col)*(HGT*WID) + sp] =
            acc2[mf][nf][j] + b4 + in[pixel*CH + col];
      }
    }
}

// ---------------------------------------------------------------------------
extern "C" void kernel_launch(void* const* d_in, const int* in_sizes, int n_in,
                              void* d_out, int out_size, void* d_ws, size_t ws_size,
                              hipStream_t stream) {
  const float* x      = (const float*)d_in[0];
  const float* pos_w  = (const float*)d_in[1];
  const float* pos_b  = (const float*)d_in[2];
  const float* ln1_g  = (const float*)d_in[3];
  const float* ln1_b  = (const float*)d_in[4];
  const float* qkv_w  = (const float*)d_in[5];
  const float* qkv_b  = (const float*)d_in[6];
  const float* lepe_w = (const float*)d_in[7];
  const float* lepe_b = (const float*)d_in[8];
  const float* wo_w   = (const float*)d_in[9];
  const float* wo_b   = (const float*)d_in[10];
  const float* ln2_g  = (const float*)d_in[11];
  const float* ln2_b  = (const float*)d_in[12];
  const float* mlp_w1 = (const float*)d_in[13];
  const float* mlp_b1 = (const float*)d_in[14];
  const float* mlp_w2 = (const float*)d_in[15];
  const float* mlp_b2 = (const float*)d_in[16];

  float* ws   = (float*)d_ws;
  float* xh   = ws;                          // NPIX*128 f32
  float* o_slot = xh + (size_t)NPIX*CH;      // NPIX*128 slot (bf16 used)
  unsigned short* obf = (unsigned short*)o_slot;
  float* qwin = o_slot + (size_t)NPIX*CH;    // 784*128
  float* kwin = qwin + (size_t)BATCH*P2*128; // 784*128
  int*   idx  = (int*)(kwin + (size_t)BATCH*P2*128); // 784*4
  unsigned short* Wq = (unsigned short*)(idx + BATCH*P2*TOPK); // 384*128
  unsigned short* Wo = Wq + 384*128;         // 128*128
  unsigned short* W1 = Wo + 128*128;         // 384*128
  unsigned short* W2 = W1 + 384*128;         // 128*384
  unsigned short* vT = W2 + 128*384;         // NPIX*128 bf16
  unsigned short* qW = vT + (size_t)NPIX*CH; // NPIX*128 bf16
  unsigned short* kW = qW + (size_t)NPIX*CH; // NPIX*128 bf16

  k_prep<<<1024, 128, 0, stream>>>(qkv_w, wo_w, mlp_w1, mlp_w2, Wq, Wo, W1, W2);
  k_posconv<<<dim3(28, BATCH), 256, 0, stream>>>(x, pos_w, pos_b, xh);
  k_route<<<BATCH*P2, 256, 0, stream>>>(xh, ln1_g, ln1_b, qkv_w, qkv_b, qwin, kwin);
  k_topk<<<BATCH*P2, 256, 0, stream>>>(qwin, kwin, idx);
  k_qkv_gemm<<<NPIX/128, 256, 0, stream>>>(xh, ln1_g, ln1_b, Wq, qkv_b, qW, kW, vT);
  k_attn_mfma<<<BATCH*P2, 256, 0, stream>>>(qW, kW, vT, idx, obf);
  k_lepe<<<dim3(28, BATCH), 256, 0, stream>>>(vT, lepe_w, lepe_b, obf);
  k_wo_mfma<<<NPIX/128, 256, 0, stream>>>(obf, Wo, wo_b, xh);
  k_mlp<<<NPIX/128, 256, 0, stream>>>(xh, ln2_g, ln2_b, W1, mlp_b1, W2, mlp_b2,
                                      (float*)d_out);
}